// Round 1
// baseline (446.662 us; speedup 1.0000x reference)
//
#include <hip/hip_runtime.h>

#define NN 512
#define EE 64
#define HIDD 256
#define OUTD 32

// -------- device-global scratch (rewritten every call; deterministic) --------
__device__ float g_hs[NN*EE];
__device__ float g_q2[NN*EE];
__device__ float g_Wcomb[3*EE*EE];     // [q,k,v] combined: W?2 @ W?
__device__ float g_Wg[4*128*64];       // packed gate weights per wave
__device__ float g_bg[4*64];
__device__ float g_Wkv[4*64*32];       // packed k2/v2 weights per wave
__device__ float g_bkv[4*32];

__device__ __forceinline__ float sigm(float x) { return 1.f / (1.f + __expf(-x)); }
__device__ __forceinline__ float tanh_f(float x) {
    float ax = fabsf(x);
    float e = __expf(-2.f * ax);
    float r = (1.f - e) / (1.f + e);
    return x >= 0.f ? r : -r;
}

// ---------------- prep1: hs (blocks 0..511) + weight packing (block 512) ----
__global__ __launch_bounds__(256) void prep1(
    const float* __restrict__ hidden, const float* __restrict__ W_hs, const float* __restrict__ b_hs,
    const float* __restrict__ W_ih, const float* __restrict__ b_ih,
    const float* __restrict__ W_hh, const float* __restrict__ b_hh,
    const float* __restrict__ Wq, const float* __restrict__ Wk, const float* __restrict__ Wv,
    const float* __restrict__ W_in, const float* __restrict__ b_in)
{
    __shared__ float part[4][64];
    const int b = blockIdx.x;
    const int tid = threadIdx.x;
    if (b < NN) {
        const int e = tid & 63, kq = tid >> 6;
        const float* hrow = hidden + b*HIDD + kq*64;
        const float* wrow = W_hs + e*HIDD + kq*64;
        float s = 0.f;
        for (int k = 0; k < 64; ++k) s = fmaf(wrow[k], hrow[k], s);
        part[kq][e] = s;
        __syncthreads();
        if (tid < 64)
            g_hs[b*EE + tid] = part[0][tid] + part[1][tid] + part[2][tid] + part[3][tid] + b_hs[tid];
    } else {
        // combined projection weights: g_Wcomb[t][a][c] = sum_m W?2[a][m] * W?[m][c]
        for (int idx = tid; idx < 3*EE*EE; idx += 256) {
            int t = idx >> 12;
            int r = idx & 4095;
            int a = r >> 6, c = r & 63;
            const float* W2 = W_in + (t*64 + a)*64;
            const float* W1 = (t == 0) ? Wq : ((t == 1) ? Wk : Wv);
            float s = 0.f;
            for (int m = 0; m < 64; ++m) s = fmaf(W2[m], W1[m*64 + c], s);
            g_Wcomb[idx] = s;
        }
        __syncthreads();
        // packed gate weights: wave w owns outs o = g*64 + w*16 + e16
        for (int idx = tid; idx < 4*128*64; idx += 256) {
            int w = idx >> 13;
            int r = idx & 8191;
            int k = r >> 6, ii = r & 63;
            int g = ii >> 4, e16 = ii & 15;
            int o = g*64 + w*16 + e16;
            g_Wg[idx] = (k < 64) ? W_ih[o*64 + k] : W_hh[o*64 + (k - 64)];
        }
        for (int idx = tid; idx < 4*64; idx += 256) {
            int w = idx >> 6, ii = idx & 63;
            int g = ii >> 4, e16 = ii & 15;
            int o = g*64 + w*16 + e16;
            g_bg[idx] = b_ih[o] + b_hh[o];
        }
        for (int idx = tid; idx < 4*64*32; idx += 256) {
            int w = idx >> 11;
            int r = idx & 2047;
            int k = r >> 5, ii = r & 31;
            int which = ii >> 4, e16 = ii & 15;
            int eo = w*16 + e16;
            g_Wkv[idx] = g_Wcomb[(1 + which)*4096 + eo*64 + k];
        }
        for (int idx = tid; idx < 4*32; idx += 256) {
            int w = idx >> 5, ii = idx & 31;
            int which = ii >> 4, e16 = ii & 15;
            g_bkv[idx] = b_in[64 + which*64 + w*16 + e16];
        }
    }
}

// ---------------- prep2: q2[b] = scale*(hs[b] @ Wq_comb.T + bq2) -------------
__global__ __launch_bounds__(64) void prep2(const float* __restrict__ b_in) {
    const int b = blockIdx.x, e = threadIdx.x;
    const float* wrow = g_Wcomb + e*64;   // t = 0 (q)
    const float* h = g_hs + b*64;
    float s = 0.f;
    for (int k = 0; k < 64; ++k) s = fmaf(wrow[k], h[k], s);
    g_q2[b*EE + e] = (s + b_in[e]) * 0.125f;   // 1/sqrt(64)
}

// ---------------- fused row kernel: one block per batch b --------------------
__global__ __launch_bounds__(256, 2) void row_kernel(
    const float* __restrict__ obs1, const float* __restrict__ obs2,
    const float* __restrict__ h0, const float* __restrict__ c0,
    const float* __restrict__ W_s, const float* __restrict__ b_s,
    const float* __restrict__ W_v, const float* __restrict__ b_v,
    const float* __restrict__ W_out, const float* __restrict__ b_out,
    const float* __restrict__ W_o, const float* __restrict__ b_o,
    float* __restrict__ out)
{
    __shared__ float X[128][65];     // [k][pair]: rows 0..63 embed, 64..127 h
    __shared__ float Ee[64][65];     // embedded e (h_new or hs) [e][pair]
    __shared__ float feat[4][64];    // rel_pos(2), rel_vel(2) per pair
    __shared__ float spart[4][64];   // per-wave score partials
    __shared__ float ctx_lds[64];
    __shared__ float av_lds[64];

    const int b = blockIdx.x;
    const int tid = threadIdx.x;
    const int lane = tid & 63;
    const int w = tid >> 6;
    const int p = lane;

    // hoisted per-thread q2 fragment (wave w owns e in [16w, 16w+16))
    float q2r[16];
#pragma unroll
    for (int e = 0; e < 16; ++e) q2r[e] = g_q2[b*64 + w*16 + e];

    // embed weights for this thread's e = lane
    float ewa, ewb, ebb;
    {
        int e = lane;
        if (e < 32) { ewa = W_s[e*2]; ewb = W_s[e*2+1]; ebb = b_s[e]; }
        else        { ewa = W_v[(e-32)*2]*4.f; ewb = W_v[(e-32)*2+1]*4.f; ebb = b_v[e-32]; }
    }

    const float ob1x = obs1[b*2], ob1y = obs1[b*2+1];
    const float ob2x = obs2[b*2], ob2y = obs2[b*2+1];
    const float velbx = ob2x - ob1x, velby = ob2y - ob1y;

    float m_run = -__builtin_inff();
    float l_lane = 0.f;
    float ctx_lane[16];
#pragma unroll
    for (int e = 0; e < 16; ++e) ctx_lane[e] = 0.f;

    const int wgbase  = __builtin_amdgcn_readfirstlane(w) * (128*64);
    const int wkvbase = __builtin_amdgcn_readfirstlane(w) * (64*32);
    const int wu      = __builtin_amdgcn_readfirstlane(w);

    for (int t = 0; t < 8; ++t) {
        const int jbase = t*64;

        // (A) features (wave 0) + stage h tile transposed into LDS
        if (tid < 64) {
            int j = jbase + tid;
            float o2x = obs2[j*2], o2y = obs2[j*2+1];
            float o1x = obs1[j*2], o1y = obs1[j*2+1];
            feat[0][tid] = o2x - ob2x;
            feat[1][tid] = o2y - ob2y;
            feat[2][tid] = (o2x - o1x) - velbx;
            feat[3][tid] = (o2y - o1y) - velby;
        }
        {
            const int p4 = tid >> 2;
            const int eq = (tid & 3) * 16;
            const float* hsrc = h0 + ((size_t)b*NN + jbase + p4)*64 + eq;
#pragma unroll
            for (int i = 0; i < 4; ++i) {
                float4 hv = *(const float4*)(hsrc + i*4);
                X[64+eq+i*4+0][p4] = hv.x; X[64+eq+i*4+1][p4] = hv.y;
                X[64+eq+i*4+2][p4] = hv.z; X[64+eq+i*4+3][p4] = hv.w;
            }
        }
        __syncthreads();

        // (B) relu embed -> X[0..63]
        {
            const int e = lane;
#pragma unroll
            for (int i = 0; i < 16; ++i) {
                int pp = w*16 + i;
                float r0, r1;
                if (e < 32) { r0 = feat[0][pp]; r1 = feat[1][pp]; }
                else        { r0 = feat[2][pp]; r1 = feat[3][pp]; }
                float v = fmaf(ewa, r0, fmaf(ewb, r1, ebb));
                X[e][pp] = v > 0.f ? v : 0.f;
            }
        }
        __syncthreads();

        // (C) LSTM gates + elementwise -> Ee
        {
            float acc[4][16];
            const float* bgp = g_bg + (wu << 6);
#pragma unroll
            for (int g = 0; g < 4; ++g)
#pragma unroll
                for (int e = 0; e < 16; ++e) acc[g][e] = bgp[g*16 + e];

            for (int k = 0; k < 128; ++k) {
                float xk = X[k][p];
                const float* wr = g_Wg + wgbase + k*64;
#pragma unroll
                for (int g = 0; g < 4; ++g)
#pragma unroll
                    for (int e = 0; e < 16; ++e)
                        acc[g][e] = fmaf(wr[g*16 + e], xk, acc[g][e]);
            }
            // c0 loaded directly (each thread reads one 64B line)
            const float* csrc = c0 + ((size_t)b*NN + jbase + p)*64 + w*16;
            float cbuf[16];
#pragma unroll
            for (int i = 0; i < 4; ++i) {
                float4 cv = *(const float4*)(csrc + i*4);
                cbuf[i*4+0] = cv.x; cbuf[i*4+1] = cv.y; cbuf[i*4+2] = cv.z; cbuf[i*4+3] = cv.w;
            }
#pragma unroll
            for (int e = 0; e < 16; ++e) {
                float ig = acc[0][e], fg = acc[1][e], gg = acc[2][e], og = acc[3][e];
                float cn = fmaf(sigm(fg), cbuf[e], sigm(ig) * tanh_f(gg));
                Ee[w*16 + e][p] = sigm(og) * tanh_f(cn);
            }
            if (jbase + p == b) {   // substitute the hs (s=0) entry
#pragma unroll
                for (int e = 0; e < 16; ++e)
                    Ee[w*16 + e][p] = g_hs[b*64 + w*16 + e];
            }
        }
        __syncthreads();

        // (D) k2/v2 projections + score partial
        float acc_v[16];
        {
            float acc_k[16];
            const float* bkvp = g_bkv + (wu << 5);
#pragma unroll
            for (int e = 0; e < 16; ++e) { acc_k[e] = bkvp[e]; acc_v[e] = bkvp[16 + e]; }
            for (int k = 0; k < 64; ++k) {
                float ek = Ee[k][p];
                const float* wr = g_Wkv + wkvbase + k*32;
#pragma unroll
                for (int e = 0; e < 16; ++e) {
                    acc_k[e] = fmaf(wr[e],      ek, acc_k[e]);
                    acc_v[e] = fmaf(wr[16 + e], ek, acc_v[e]);
                }
            }
            float sp = 0.f;
#pragma unroll
            for (int e = 0; e < 16; ++e) sp = fmaf(q2r[e], acc_k[e], sp);
            spart[w][p] = sp;
        }
        __syncthreads();

        // (E) online softmax update (all waves compute identical stats)
        {
            float s_p = spart[0][p] + spart[1][p] + spart[2][p] + spart[3][p];
            float tm = s_p;
#pragma unroll
            for (int m = 1; m < 64; m <<= 1) tm = fmaxf(tm, __shfl_xor(tm, m, 64));
            float m_new = fmaxf(m_run, tm);
            float corr = __expf(m_run - m_new);   // exp(-inf)=0 on first tile
            float wp = __expf(s_p - m_new);
            l_lane = fmaf(l_lane, corr, wp);
#pragma unroll
            for (int e = 0; e < 16; ++e) ctx_lane[e] = fmaf(ctx_lane[e], corr, wp * acc_v[e]);
            m_run = m_new;
        }
        __syncthreads();
    }

    // final reductions across lanes (p)
    float l_tot = l_lane;
#pragma unroll
    for (int m = 1; m < 64; m <<= 1) l_tot += __shfl_xor(l_tot, m, 64);
    const float inv_l = 1.f / l_tot;
#pragma unroll
    for (int e = 0; e < 16; ++e) {
        float s = ctx_lane[e];
#pragma unroll
        for (int m = 1; m < 64; m <<= 1) s += __shfl_xor(s, m, 64);
        if (lane == 0) ctx_lds[w*16 + e] = s * inv_l;
    }
    __syncthreads();

    if (tid < 64) {
        const int e = tid;
        float s = b_out[e];
        const float* wrow = W_out + e*64;
        for (int k = 0; k < 64; ++k) s = fmaf(wrow[k], ctx_lds[k], s);
        av_lds[e] = s;
    }
    __syncthreads();
    if (tid < 32) {
        const int o = tid;
        float s = b_o[o];
        const float* wrow = W_o + o*64;
        for (int k = 0; k < 64; ++k) s = fmaf(wrow[k], av_lds[k], s);
        out[b*OUTD + o] = s;
    }
}

extern "C" void kernel_launch(void* const* d_in, const int* in_sizes, int n_in,
                              void* d_out, int out_size, void* d_ws, size_t ws_size,
                              hipStream_t stream) {
    const float* hidden = (const float*)d_in[0];
    const float* obs1   = (const float*)d_in[1];
    const float* obs2   = (const float*)d_in[2];
    const float* h0     = (const float*)d_in[3];
    const float* c0     = (const float*)d_in[4];
    const float* W_s    = (const float*)d_in[5];
    const float* b_s    = (const float*)d_in[6];
    const float* W_v    = (const float*)d_in[7];
    const float* b_v    = (const float*)d_in[8];
    const float* W_hs   = (const float*)d_in[9];
    const float* b_hs   = (const float*)d_in[10];
    const float* W_ih   = (const float*)d_in[11];
    const float* b_ih   = (const float*)d_in[12];
    const float* W_hh   = (const float*)d_in[13];
    const float* b_hh   = (const float*)d_in[14];
    const float* Wq     = (const float*)d_in[15];
    const float* Wk     = (const float*)d_in[16];
    const float* Wv     = (const float*)d_in[17];
    const float* W_in   = (const float*)d_in[18];
    const float* b_in   = (const float*)d_in[19];
    const float* W_out  = (const float*)d_in[20];
    const float* b_out  = (const float*)d_in[21];
    const float* W_o    = (const float*)d_in[22];
    const float* b_o    = (const float*)d_in[23];

    prep1<<<dim3(NN + 1), dim3(256), 0, stream>>>(
        hidden, W_hs, b_hs, W_ih, b_ih, W_hh, b_hh, Wq, Wk, Wv, W_in, b_in);
    prep2<<<dim3(NN), dim3(64), 0, stream>>>(b_in);
    row_kernel<<<dim3(NN), dim3(256), 0, stream>>>(
        obs1, obs2, h0, c0, W_s, b_s, W_v, b_v, W_out, b_out, W_o, b_o,
        (float*)d_out);
}

// Round 2
// 197.206 us; speedup vs baseline: 2.2649x; 2.2649x over previous
//
#include <hip/hip_runtime.h>
#include <cstdint>

#define NN 512
#define EE 64
#define HIDD 256
#define OUTD 32

typedef __bf16 bf16x8 __attribute__((ext_vector_type(8)));
typedef float f32x4 __attribute__((ext_vector_type(4)));

// -------- device-global scratch (fully rewritten every call) --------
__device__ float g_hs[NN*EE];
__device__ float g_qk[NN*EE];          // qk[b] = Wk_comb^T @ q2[b]
__device__ float g_Wcomb[3*EE*EE];     // [q,k,v] combined: W?2 @ W?
__device__ uint4 g_Ag[4096];           // packed A-fragments (bf16) of interleaved gate weights
__device__ float g_biasI[256];         // interleaved gate bias, r = 4e+g
__device__ float g_embW[EE*4];         // per-e embed weights (a,b,bias,0)
__device__ float g_Wtot[OUTD*EE];      // W_o @ W_out @ Wv_comb
__device__ float g_btot[OUTD];         // W_o @ (W_out @ bv2 + b_out) + b_o

__device__ __forceinline__ float sigm(float x){ return 1.f/(1.f+__expf(-x)); }
__device__ __forceinline__ float tanh_f(float x){
  float ax = fabsf(x);
  float e = __expf(-2.f*ax);
  float r = (1.f-e)/(1.f+e);
  return x >= 0.f ? r : -r;
}
__device__ __forceinline__ uint32_t f2bf(float x){
  uint32_t u = __builtin_bit_cast(uint32_t, x);
  u += 0x7fffu + ((u>>16)&1u);          // RNE
  return u>>16;
}
__device__ __forceinline__ uint32_t pk2(float lo, float hi){
  return f2bf(lo) | (f2bf(hi)<<16);
}

// ---------------- prep1: hs (blocks 0..511) + weight packing (block 512) ----
__global__ __launch_bounds__(256) void prep1(
    const float* __restrict__ hidden, const float* __restrict__ W_hs, const float* __restrict__ b_hs,
    const float* __restrict__ W_ih, const float* __restrict__ b_ih,
    const float* __restrict__ W_hh, const float* __restrict__ b_hh,
    const float* __restrict__ Wq, const float* __restrict__ Wk, const float* __restrict__ Wv,
    const float* __restrict__ W_in,
    const float* __restrict__ W_s, const float* __restrict__ b_s,
    const float* __restrict__ W_v, const float* __restrict__ b_v)
{
    __shared__ float part[4][64];
    const int b = blockIdx.x;
    const int tid = threadIdx.x;
    if (b < NN) {
        const int e = tid & 63, kq = tid >> 6;
        const float* hrow = hidden + b*HIDD + kq*64;
        const float* wrow = W_hs + e*HIDD + kq*64;
        float s = 0.f;
        for (int k = 0; k < 64; ++k) s = fmaf(wrow[k], hrow[k], s);
        part[kq][e] = s;
        __syncthreads();
        if (tid < 64)
            g_hs[b*EE + tid] = part[0][tid] + part[1][tid] + part[2][tid] + part[3][tid] + b_hs[tid];
    } else {
        // combined projection weights
        for (int idx = tid; idx < 3*EE*EE; idx += 256) {
            int t = idx >> 12, rr = idx & 4095, a = rr >> 6, c = rr & 63;
            const float* W2 = W_in + (t*64 + a)*64;
            const float* W1 = (t == 0) ? Wq : ((t == 1) ? Wk : Wv);
            float s = 0.f;
            for (int m = 0; m < 64; ++m) s = fmaf(W2[m], W1[m*64 + c], s);
            g_Wcomb[idx] = s;
        }
        // packed A-fragments: entry ((w*16 + mh*4 + kh)*64 + lane) -> 8 bf16
        for (int idx = tid; idx < 4096; idx += 256) {
            int w = idx >> 10, mh = (idx >> 8) & 3, kh = (idx >> 6) & 3, lane = idx & 63;
            int grow = 16*(4*w + mh) + (lane & 15);   // interleaved row r = 4e+g
            int e = grow >> 2, g = grow & 3, o = g*64 + e;
            int kb = 32*kh + 8*(lane >> 4);
            float v[8];
#pragma unroll
            for (int i = 0; i < 8; ++i) {
                int k = kb + i;
                v[i] = (k < 64) ? W_ih[o*64 + k] : W_hh[o*64 + (k - 64)];
            }
            uint4 u;
            u.x = pk2(v[0], v[1]); u.y = pk2(v[2], v[3]);
            u.z = pk2(v[4], v[5]); u.w = pk2(v[6], v[7]);
            g_Ag[idx] = u;
        }
        for (int idx = tid; idx < 256; idx += 256) {
            int e = idx >> 2, g = idx & 3, o = g*64 + e;
            g_biasI[idx] = b_ih[o] + b_hh[o];
        }
        if (tid < 64) {
            int e = tid;
            if (e < 32) {
                g_embW[e*4+0] = W_s[e*2]; g_embW[e*4+1] = W_s[e*2+1]; g_embW[e*4+2] = b_s[e];
            } else {
                g_embW[e*4+0] = 4.f*W_v[(e-32)*2]; g_embW[e*4+1] = 4.f*W_v[(e-32)*2+1]; g_embW[e*4+2] = b_v[e-32];
            }
            g_embW[e*4+3] = 0.f;
        }
    }
}

// ---------------- prepB: qk per row (blocks 0..511) + fused output W (512) --
__global__ __launch_bounds__(256) void prepB(
    const float* __restrict__ b_in, const float* __restrict__ W_out, const float* __restrict__ b_out,
    const float* __restrict__ W_o, const float* __restrict__ b_o)
{
    const int b = blockIdx.x, tid = threadIdx.x;
    if (b < NN) {
        __shared__ float q2s[64];
        if (tid < 64) {
            const float* wrow = g_Wcomb + tid*64;          // Wq_comb row
            const float* h = g_hs + b*64;
            float s = 0.f;
            for (int k = 0; k < 64; ++k) s = fmaf(wrow[k], h[k], s);
            q2s[tid] = (s + b_in[tid]) * 0.125f;           // * 1/sqrt(64)
        }
        __syncthreads();
        if (tid < 64) {
            float s = 0.f;
            for (int a = 0; a < 64; ++a) s = fmaf(g_Wcomb[4096 + a*64 + tid], q2s[a], s);
            g_qk[b*64 + tid] = s;
        }
    } else {
        __shared__ float Wtmp[64*64];
        __shared__ float bb[64];
        for (int idx = tid; idx < 4096; idx += 256) {
            int i = idx >> 6, j = idx & 63;
            float s = 0.f;
            for (int k = 0; k < 64; ++k) s = fmaf(W_out[i*64 + k], g_Wcomb[2*4096 + k*64 + j], s);
            Wtmp[idx] = s;
        }
        if (tid < 64) {
            float s = 0.f;
            for (int k = 0; k < 64; ++k) s = fmaf(W_out[tid*64 + k], b_in[128 + k], s);
            bb[tid] = s + b_out[tid];
        }
        __syncthreads();
        for (int idx = tid; idx < OUTD*64; idx += 256) {
            int o = idx >> 6, j = idx & 63;
            float s = 0.f;
            for (int i = 0; i < 64; ++i) s = fmaf(W_o[o*64 + i], Wtmp[i*64 + j], s);
            g_Wtot[idx] = s;
        }
        if (tid < OUTD) {
            float s = 0.f;
            for (int i = 0; i < 64; ++i) s = fmaf(W_o[tid*64 + i], bb[i], s);
            g_btot[tid] = s + b_o[tid];
        }
    }
}

// ---------------- fused row kernel: one block (4 waves) per batch row b -----
__global__ __launch_bounds__(256, 2) void row_kernel(
    const float* __restrict__ obs1, const float* __restrict__ obs2,
    const float* __restrict__ h0, const float* __restrict__ c0,
    float* __restrict__ out)
{
    __shared__ __align__(16) unsigned char Xs[64*288];  // [pair][K=128 bf16], 288B rows
    __shared__ float feat[64][4];
    __shared__ float embw[64][4];
    __shared__ float spart[4][64];
    __shared__ float wfull[64];
    __shared__ float ctxE[64];

    const int b = blockIdx.x, tid = threadIdx.x;
    const int w = tid >> 6, l = tid & 63, r = l & 15, q = l >> 4;
    const int p4 = tid >> 2, oc = (tid & 3) * 16;

    if (tid < 64) *(float4*)&embw[tid][0] = *(const float4*)(g_embW + tid*4);

    // hoisted A-fragments (reused for all 8 tiles)
    uint4 Afr[4][4];
#pragma unroll
    for (int mh = 0; mh < 4; ++mh)
#pragma unroll
        for (int kh = 0; kh < 4; ++kh)
            Afr[mh][kh] = g_Ag[((w*16 + mh*4 + kh) << 6) + l];

    f32x4 biasv[4];
#pragma unroll
    for (int mh = 0; mh < 4; ++mh) {
        float4 t4 = *(const float4*)(g_biasI + (4*w + mh)*16 + 4*q);
        f32x4 bv; bv[0] = t4.x; bv[1] = t4.y; bv[2] = t4.z; bv[3] = t4.w;
        biasv[mh] = bv;
    }
    float qkr[4], hsd[4];
#pragma unroll
    for (int mh = 0; mh < 4; ++mh) {
        int e = 16*w + 4*mh + q;
        qkr[mh] = g_qk[b*64 + e];
        hsd[mh] = g_hs[b*64 + e];
    }

    const float ob1x = obs1[b*2], ob1y = obs1[b*2+1];
    const float ob2x = obs2[b*2], ob2y = obs2[b*2+1];
    const float velbx = ob2x - ob1x, velby = ob2y - ob1y;

    float m_run = -__builtin_inff(), l_run = 0.f;
    float ctxa[4] = {0.f, 0.f, 0.f, 0.f};

    const float* hrow = h0 + (size_t)b*NN*EE;
    float4 hbuf[4];
#pragma unroll
    for (int i = 0; i < 4; ++i) hbuf[i] = *(const float4*)(hrow + (size_t)p4*EE + oc + 4*i);

    for (int t = 0; t < 8; ++t) {
        const int jbase = t*64;
        // --- phase A: features + stage h tile (bf16) into Xs[.., 128..256) ---
        if (tid < 64) {
            int j = jbase + tid;
            float o2x = obs2[j*2], o2y = obs2[j*2+1];
            float o1x = obs1[j*2], o1y = obs1[j*2+1];
            feat[tid][0] = o2x - ob2x;
            feat[tid][1] = o2y - ob2y;
            feat[tid][2] = (o2x - o1x) - velbx;
            feat[tid][3] = (o2y - o1y) - velby;
        }
        {
            uint4 u0, u1;
            u0.x = pk2(hbuf[0].x, hbuf[0].y); u0.y = pk2(hbuf[0].z, hbuf[0].w);
            u0.z = pk2(hbuf[1].x, hbuf[1].y); u0.w = pk2(hbuf[1].z, hbuf[1].w);
            u1.x = pk2(hbuf[2].x, hbuf[2].y); u1.y = pk2(hbuf[2].z, hbuf[2].w);
            u1.z = pk2(hbuf[3].x, hbuf[3].y); u1.w = pk2(hbuf[3].z, hbuf[3].w);
            *(uint4*)(Xs + p4*288 + 128 + oc*2)      = u0;
            *(uint4*)(Xs + p4*288 + 128 + oc*2 + 16) = u1;
        }
        __syncthreads();
        // --- phase B: relu embed -> Xs[.., 0..128) ---
        {
            float4 f4 = *(const float4*)&feat[p4][0];
            uint32_t uu[8];
#pragma unroll
            for (int i2 = 0; i2 < 8; ++i2) {
                int e0 = oc + 2*i2, e1 = e0 + 1;
                float4 w0 = *(const float4*)&embw[e0][0];
                float4 w1 = *(const float4*)&embw[e1][0];
                float r00 = (e0 < 32) ? f4.x : f4.z, r01 = (e0 < 32) ? f4.y : f4.w;
                float r10 = (e1 < 32) ? f4.x : f4.z, r11 = (e1 < 32) ? f4.y : f4.w;
                float v0 = fmaxf(fmaf(w0.x, r00, fmaf(w0.y, r01, w0.z)), 0.f);
                float v1 = fmaxf(fmaf(w1.x, r10, fmaf(w1.y, r11, w1.z)), 0.f);
                uu[i2] = pk2(v0, v1);
            }
            uint4 u0, u1;
            u0.x = uu[0]; u0.y = uu[1]; u0.z = uu[2]; u0.w = uu[3];
            u1.x = uu[4]; u1.y = uu[5]; u1.z = uu[6]; u1.w = uu[7];
            *(uint4*)(Xs + p4*288 + oc*2)      = u0;
            *(uint4*)(Xs + p4*288 + oc*2 + 16) = u1;
        }
        __syncthreads();
        // --- c0 prefetch (consumed in phase D; overlaps MFMA) ---
        float cpre[4][4];
#pragma unroll
        for (int mh = 0; mh < 4; ++mh) {
            int e = 16*w + 4*mh + q;
#pragma unroll
            for (int nh = 0; nh < 4; ++nh) {
                int p = 16*nh + r;
                cpre[mh][nh] = c0[((size_t)b*NN + jbase + p)*EE + e];
            }
        }
        // --- phase C: gates MFMA (M=64 rows/wave interleaved, N=64, K=128) ---
        f32x4 acc[4][4];
#pragma unroll
        for (int mh = 0; mh < 4; ++mh)
#pragma unroll
            for (int nh = 0; nh < 4; ++nh) acc[mh][nh] = biasv[mh];
#pragma unroll
        for (int kh = 0; kh < 4; ++kh) {
            bf16x8 Bf[4];
#pragma unroll
            for (int nh = 0; nh < 4; ++nh)
                Bf[nh] = __builtin_bit_cast(bf16x8, *(const uint4*)(Xs + (16*nh + r)*288 + kh*64 + q*16));
#pragma unroll
            for (int mh = 0; mh < 4; ++mh) {
                bf16x8 Af = __builtin_bit_cast(bf16x8, Afr[mh][kh]);
#pragma unroll
                for (int nh = 0; nh < 4; ++nh)
                    acc[mh][nh] = __builtin_amdgcn_mfma_f32_16x16x32_bf16(Af, Bf[nh], acc[mh][nh], 0, 0, 0);
            }
        }
        // --- prefetch next tile's h (latency hidden under phases D/E) ---
        if (t < 7) {
#pragma unroll
            for (int i = 0; i < 4; ++i)
                hbuf[i] = *(const float4*)(hrow + ((size_t)(jbase + 64) + p4)*EE + oc + 4*i);
        }
        // --- phase D: LSTM elementwise + score partials ---
        float sp[4] = {0.f, 0.f, 0.f, 0.f};
        float Eev[4][4];
#pragma unroll
        for (int mh = 0; mh < 4; ++mh) {
#pragma unroll
            for (int nh = 0; nh < 4; ++nh) {
                f32x4 g4 = acc[mh][nh];   // [i,f,g,o] gates of (e, p)
                float cn = fmaf(sigm(g4[1]), cpre[mh][nh], sigm(g4[0]) * tanh_f(g4[2]));
                float hh = sigm(g4[3]) * tanh_f(cn);
                if (jbase + 16*nh + r == b) hh = hsd[mh];   // diagonal -> hs entry
                Eev[mh][nh] = hh;
                sp[nh] = fmaf(qkr[mh], hh, sp[nh]);
            }
        }
#pragma unroll
        for (int nh = 0; nh < 4; ++nh) {
            float v = sp[nh];
            v += __shfl_xor(v, 16, 64);
            v += __shfl_xor(v, 32, 64);
            if (q == 0) spart[w][16*nh + r] = v;
        }
        __syncthreads();
        // --- phase E: online softmax + ctx accumulation ---
        {
            float s_p = spart[0][l] + spart[1][l] + spart[2][l] + spart[3][l];
            float tm = s_p;
#pragma unroll
            for (int off = 1; off < 64; off <<= 1) tm = fmaxf(tm, __shfl_xor(tm, off, 64));
            float m_new = fmaxf(m_run, tm);
            float corr = __expf(m_run - m_new);    // first tile: exp(-inf)=0
            float wp = __expf(s_p - m_new);
            l_run = fmaf(l_run, corr, wp);
            m_run = m_new;
            if (w == 0) wfull[l] = wp;
            __syncthreads();
            float wn[4];
#pragma unroll
            for (int nh = 0; nh < 4; ++nh) wn[nh] = wfull[16*nh + r];
#pragma unroll
            for (int mh = 0; mh < 4; ++mh) {
                float a = ctxa[mh] * corr;
#pragma unroll
                for (int nh = 0; nh < 4; ++nh) a = fmaf(wn[nh], Eev[mh][nh], a);
                ctxa[mh] = a;
            }
        }
    }
    // --- epilogue: normalize, reduce ctxE, fused output projection ---
    float l_tot = l_run;
#pragma unroll
    for (int off = 1; off < 64; off <<= 1) l_tot += __shfl_xor(l_tot, off, 64);
    float inv = 1.f / l_tot;
#pragma unroll
    for (int mh = 0; mh < 4; ++mh) {
        float v = ctxa[mh];
#pragma unroll
        for (int off = 1; off < 16; off <<= 1) v += __shfl_xor(v, off, 64);
        if (r == 0) ctxE[16*w + 4*mh + q] = v * inv;
    }
    __syncthreads();
    if (tid < OUTD) {
        float s = g_btot[tid];
        const float* wr2 = g_Wtot + tid*64;
        for (int k = 0; k < 64; ++k) s = fmaf(wr2[k], ctxE[k], s);
        out[b*OUTD + tid] = s;
    }
}

extern "C" void kernel_launch(void* const* d_in, const int* in_sizes, int n_in,
                              void* d_out, int out_size, void* d_ws, size_t ws_size,
                              hipStream_t stream) {
    const float* hidden = (const float*)d_in[0];
    const float* obs1   = (const float*)d_in[1];
    const float* obs2   = (const float*)d_in[2];
    const float* h0     = (const float*)d_in[3];
    const float* c0     = (const float*)d_in[4];
    const float* W_s    = (const float*)d_in[5];
    const float* b_s    = (const float*)d_in[6];
    const float* W_v    = (const float*)d_in[7];
    const float* b_v    = (const float*)d_in[8];
    const float* W_hs   = (const float*)d_in[9];
    const float* b_hs   = (const float*)d_in[10];
    const float* W_ih   = (const float*)d_in[11];
    const float* b_ih   = (const float*)d_in[12];
    const float* W_hh   = (const float*)d_in[13];
    const float* b_hh   = (const float*)d_in[14];
    const float* Wq     = (const float*)d_in[15];
    const float* Wk     = (const float*)d_in[16];
    const float* Wv     = (const float*)d_in[17];
    const float* W_in   = (const float*)d_in[18];
    const float* b_in   = (const float*)d_in[19];
    const float* W_out  = (const float*)d_in[20];
    const float* b_out  = (const float*)d_in[21];
    const float* W_o    = (const float*)d_in[22];
    const float* b_o    = (const float*)d_in[23];

    prep1<<<dim3(NN + 1), dim3(256), 0, stream>>>(
        hidden, W_hs, b_hs, W_ih, b_ih, W_hh, b_hh, Wq, Wk, Wv, W_in, W_s, b_s, W_v, b_v);
    prepB<<<dim3(NN + 1), dim3(256), 0, stream>>>(b_in, W_out, b_out, W_o, b_o);
    row_kernel<<<dim3(NN), dim3(256), 0, stream>>>(obs1, obs2, h0, c0, (float*)d_out);
}

// Round 3
// 178.799 us; speedup vs baseline: 2.4981x; 1.1029x over previous
//
#include <hip/hip_runtime.h>
#include <cstdint>

#define NN 512
#define EE 64
#define HIDD 256
#define OUTD 32
#define L2E 1.4426950408889634f

typedef __bf16 bf16x8 __attribute__((ext_vector_type(8)));
typedef float f32x4 __attribute__((ext_vector_type(4)));

// -------- device-global scratch (fully rewritten every call; deterministic) --------
__device__ float g_hs[NN*EE];
__device__ float g_qk[NN*EE];          // log2e * (Wk_comb^T @ q2)  per row
__device__ float g_Wcomb[3*EE*EE];     // [q,k,v] combined: W?2 @ W?
__device__ float g_WhsT[HIDD*EE];      // W_hs transposed [k][e]
__device__ float g_M2T[EE*EE];         // M2T[c][e] = L2E*scale*sum_a Wk[a][e]*Wq[a][c]
__device__ float g_cvec[EE];
__device__ uint4 g_Ag2[4096];          // bf16 A-fragments, gate-scaled, frag ((w*4+mh)*4+kh)
__device__ float g_biasI[256];         // [e][gate], gate-scaled
__device__ float g_embW[EE*4];
__device__ float g_Wtot[OUTD*EE];      // W_o @ W_out @ Wv_comb
__device__ float g_btot[OUTD];
__device__ float g_part[2*NN][68];     // per (b,half): ctx_u[64], m, l

__device__ __forceinline__ float ex2(float x){ return __builtin_amdgcn_exp2f(x); }
__device__ __forceinline__ float rcp_(float x){ return __builtin_amdgcn_rcpf(x); }

// ---------------- prepW: weight packing ----------------
__global__ __launch_bounds__(256) void prepW(
    const float* __restrict__ W_ih, const float* __restrict__ b_ih,
    const float* __restrict__ W_hh, const float* __restrict__ b_hh,
    const float* __restrict__ Wq, const float* __restrict__ Wk, const float* __restrict__ Wv,
    const float* __restrict__ W_in, const float* __restrict__ W_hs,
    const float* __restrict__ W_s, const float* __restrict__ b_s,
    const float* __restrict__ W_v, const float* __restrict__ b_v)
{
    const int blk = blockIdx.x, tid = threadIdx.x;
    if (blk < 4) {
        // pack A fragments for wave w = blk, rows interleaved so lane e's are contiguous
        const int w = blk;
#pragma unroll
        for (int ii = 0; ii < 4; ++ii) {
            int idx = ii*256 + tid;            // (mh*4+kh)*64 + lane
            int lane = idx & 63;
            int kh = (idx >> 6) & 3;
            int mh = idx >> 8;
            int m = lane & 15;
            int qq = m >> 2, gate = m & 3;
            int e = 16*w + 4*qq + mh;
            int o = gate*64 + e;
            int kb = kh*32 + (lane >> 4)*8;
            float sc = (gate == 2) ? (-2.f*L2E) : (-L2E);
            bf16x8 vv;
#pragma unroll
            for (int j = 0; j < 8; ++j) {
                int k = kb + j;
                float raw = (k < 64) ? W_ih[o*64 + k] : W_hh[o*64 + (k - 64)];
                vv[j] = (__bf16)(sc * raw);
            }
            g_Ag2[(((w*4 + mh)*4 + kh) << 6) + lane] = __builtin_bit_cast(uint4, vv);
        }
    } else if (blk == 4) {
        // biasI (scaled, [e][gate]) + embW + W_hsT
        {
            int e = tid >> 2, gate = tid & 3, o = gate*64 + e;
            float sc = (gate == 2) ? (-2.f*L2E) : (-L2E);
            g_biasI[tid] = sc * (b_ih[o] + b_hh[o]);
        }
        if (tid < 64) {
            int e = tid;
            if (e < 32) {
                g_embW[e*4+0] = W_s[e*2]; g_embW[e*4+1] = W_s[e*2+1]; g_embW[e*4+2] = b_s[e];
            } else {
                g_embW[e*4+0] = 4.f*W_v[(e-32)*2]; g_embW[e*4+1] = 4.f*W_v[(e-32)*2+1]; g_embW[e*4+2] = b_v[e-32];
            }
            g_embW[e*4+3] = 0.f;
        }
        for (int idx = tid; idx < HIDD*EE; idx += 256) {
            int k = idx >> 6, e = idx & 63;
            g_WhsT[idx] = W_hs[e*HIDD + k];
        }
    } else {
        int t = blk - 5;                      // 0,1,2 -> q,k,v
        const float* W2 = W_in + t*4096;
        const float* W1 = (t == 0) ? Wq : ((t == 1) ? Wk : Wv);
        for (int idx = tid; idx < 4096; idx += 256) {
            int a = idx >> 6, c = idx & 63;
            float s = 0.f;
            for (int m = 0; m < 64; ++m) s = fmaf(W2[a*64 + m], W1[m*64 + c], s);
            g_Wcomb[t*4096 + idx] = s;
        }
    }
}

// ---------------- prepW2: M2T/cvec (blk0) + fused output proj (blk1) --------
__global__ __launch_bounds__(256) void prepW2(
    const float* __restrict__ b_in, const float* __restrict__ W_out,
    const float* __restrict__ b_out, const float* __restrict__ W_o,
    const float* __restrict__ b_o)
{
    const int tid = threadIdx.x;
    if (blockIdx.x == 0) {
        const float* Wqc = g_Wcomb;
        const float* Wkc = g_Wcomb + 4096;
        for (int idx = tid; idx < 4096; idx += 256) {
            int c = idx >> 6, e = idx & 63;
            float s = 0.f;
            for (int a = 0; a < 64; ++a) s = fmaf(Wkc[a*64 + e], Wqc[a*64 + c], s);
            g_M2T[idx] = s * (L2E * 0.125f);
        }
        if (tid < 64) {
            float s = 0.f;
            for (int a = 0; a < 64; ++a) s = fmaf(g_Wcomb[4096 + a*64 + tid], b_in[a], s);
            g_cvec[tid] = s * (L2E * 0.125f);
        }
    } else {
        __shared__ float Wtmp[4096];
        __shared__ float bb[64];
        for (int idx = tid; idx < 4096; idx += 256) {
            int i = idx >> 6, jj = idx & 63;
            float s = 0.f;
            for (int k = 0; k < 64; ++k) s = fmaf(W_out[i*64 + k], g_Wcomb[2*4096 + k*64 + jj], s);
            Wtmp[idx] = s;
        }
        if (tid < 64) {
            float s = 0.f;
            for (int k = 0; k < 64; ++k) s = fmaf(W_out[tid*64 + k], b_in[128 + k], s);
            bb[tid] = s + b_out[tid];
        }
        __syncthreads();
        for (int idx = tid; idx < OUTD*64; idx += 256) {
            int o = idx >> 6, jj = idx & 63;
            float s = 0.f;
            for (int i = 0; i < 64; ++i) s = fmaf(W_o[o*64 + i], Wtmp[i*64 + jj], s);
            g_Wtot[idx] = s;
        }
        if (tid < OUTD) {
            float s = 0.f;
            for (int i = 0; i < 64; ++i) s = fmaf(W_o[tid*64 + i], bb[i], s);
            g_btot[tid] = s + b_o[tid];
        }
    }
}

// ---------------- prepH: per-row hs and qk (coalesced) ----------------------
__global__ __launch_bounds__(256) void prepH(
    const float* __restrict__ hidden, const float* __restrict__ b_hs)
{
    __shared__ float hid[HIDD];
    __shared__ float part[4][64];
    __shared__ float hsL[64];
    const int b = blockIdx.x, tid = threadIdx.x;
    hid[tid] = hidden[b*HIDD + tid];
    __syncthreads();
    const int e = tid & 63, kq = tid >> 6;
    float s = 0.f;
    for (int k = 0; k < 64; ++k) {
        int kk = kq*64 + k;
        s = fmaf(g_WhsT[kk*64 + e], hid[kk], s);
    }
    part[kq][e] = s;
    __syncthreads();
    if (tid < 64) {
        float v = part[0][tid] + part[1][tid] + part[2][tid] + part[3][tid] + b_hs[tid];
        g_hs[b*EE + tid] = v;
        hsL[tid] = v;
    }
    __syncthreads();
    float s2 = 0.f;
    for (int k = 0; k < 16; ++k) {
        int kk = kq*16 + k;
        s2 = fmaf(g_M2T[kk*64 + e], hsL[kk], s2);
    }
    part[kq][e] = s2;
    __syncthreads();
    if (tid < 64)
        g_qk[b*EE + tid] = part[0][tid] + part[1][tid] + part[2][tid] + part[3][tid] + g_cvec[tid];
}

// ---------------- row kernel: one block per (b, half), 4 tiles each ---------
__global__ __launch_bounds__(256, 3) void row_kernel(
    const float* __restrict__ obs1, const float* __restrict__ obs2,
    const float* __restrict__ h0, const float* __restrict__ c0)
{
    __shared__ __align__(16) unsigned short Xs[64*72];   // embed tile [p][72 bf16] (144B rows)
    __shared__ float spart[4][64];
    __shared__ float embw[64][4];

    const int bh = blockIdx.x;
    const int b = bh >> 1, half = bh & 1;
    const int tid = threadIdx.x;
    const int w = tid >> 6, l = tid & 63;
    const int r = l & 15, q = l >> 4;
    const int p4 = tid >> 2, a4 = tid & 3;
    const int ebase = 16*w + 4*q;

    if (tid < 64) *(float4*)&embw[tid][0] = *(const float4*)(g_embW + tid*4);

    const float4 qk4 = *(const float4*)(g_qk + b*64 + ebase);
    const float4 hs4 = *(const float4*)(g_hs + b*64 + ebase);
    f32x4 qkr; qkr[0]=qk4.x; qkr[1]=qk4.y; qkr[2]=qk4.z; qkr[3]=qk4.w;
    f32x4 hsd; hsd[0]=hs4.x; hsd[1]=hs4.y; hsd[2]=hs4.z; hsd[3]=hs4.w;
    f32x4 biasv[4];
#pragma unroll
    for (int mh = 0; mh < 4; ++mh) {
        float4 t4 = *(const float4*)(g_biasI + (ebase + mh)*4);
        biasv[mh][0]=t4.x; biasv[mh][1]=t4.y; biasv[mh][2]=t4.z; biasv[mh][3]=t4.w;
    }

    const float ob1x = obs1[b*2], ob1y = obs1[b*2+1];
    const float ob2x = obs2[b*2], ob2y = obs2[b*2+1];
    const float velbx = ob2x - ob1x, velby = ob2y - ob1y;

    float m_run = -__builtin_inff(), l_run = 0.f;
    float ctxa[4] = {0.f, 0.f, 0.f, 0.f};
    const size_t rowbase = (size_t)b * NN * EE;

    __syncthreads();   // embw visible

    for (int t = 0; t < 4; ++t) {
        const int jbase = half*256 + t*64;

        // ---- embed -> Xs (each thread: row p4, e in [16*a4, 16*a4+16)) ----
        {
            const int j = jbase + p4;
            const float2 o2 = *(const float2*)(obs2 + j*2);
            const float2 o1 = *(const float2*)(obs1 + j*2);
            const float fx = o2.x - ob2x, fy = o2.y - ob2y;
            const float gx = (o2.x - o1.x) - velbx, gy = (o2.y - o1.y) - velby;
            const bool sph = (a4 < 2);
            const float u0 = sph ? fx : gx, u1 = sph ? fy : gy;
            bf16x8 pa, pb;
#pragma unroll
            for (int i = 0; i < 8; ++i) {
                float4 wv = *(const float4*)&embw[16*a4 + i][0];
                pa[i] = (__bf16)fmaxf(fmaf(wv.x, u0, fmaf(wv.y, u1, wv.z)), 0.f);
            }
#pragma unroll
            for (int i = 0; i < 8; ++i) {
                float4 wv = *(const float4*)&embw[16*a4 + 8 + i][0];
                pb[i] = (__bf16)fmaxf(fmaf(wv.x, u0, fmaf(wv.y, u1, wv.z)), 0.f);
            }
            *(bf16x8*)(&Xs[p4*72 + 16*a4])     = pa;
            *(bf16x8*)(&Xs[p4*72 + 16*a4 + 8]) = pb;
        }
        __syncthreads();

        // ---- c0 slice: 4 coalesced float4 (e contiguous thanks to new interleave) ----
        f32x4 cpre[4];
#pragma unroll
        for (int nh = 0; nh < 4; ++nh) {
            float4 cc = *(const float4*)(c0 + rowbase + (size_t)(jbase + 16*nh + r)*EE + ebase);
            cpre[nh][0]=cc.x; cpre[nh][1]=cc.y; cpre[nh][2]=cc.z; cpre[nh][3]=cc.w;
        }

        // ---- gates MFMA: kh-outer, acc-resident; A streamed from L2, h direct ----
        f32x4 acc[4][4];
#pragma unroll
        for (int mh = 0; mh < 4; ++mh)
#pragma unroll
            for (int nh = 0; nh < 4; ++nh) acc[mh][nh] = biasv[mh];
#pragma unroll
        for (int kh = 0; kh < 4; ++kh) {
            bf16x8 Bf[4];
            if (kh < 2) {
#pragma unroll
                for (int nh = 0; nh < 4; ++nh)
                    Bf[nh] = *(const bf16x8*)(&Xs[(16*nh + r)*72 + kh*32 + q*8]);
            } else {
#pragma unroll
                for (int nh = 0; nh < 4; ++nh) {
                    const float* hp = h0 + rowbase + (size_t)(jbase + 16*nh + r)*EE + (kh-2)*32 + q*8;
                    float4 f0 = *(const float4*)(hp);
                    float4 f1 = *(const float4*)(hp + 4);
                    bf16x8 o;
                    o[0]=(__bf16)f0.x; o[1]=(__bf16)f0.y; o[2]=(__bf16)f0.z; o[3]=(__bf16)f0.w;
                    o[4]=(__bf16)f1.x; o[5]=(__bf16)f1.y; o[6]=(__bf16)f1.z; o[7]=(__bf16)f1.w;
                    Bf[nh] = o;
                }
            }
            bf16x8 Af[4];
#pragma unroll
            for (int mh = 0; mh < 4; ++mh)
                Af[mh] = __builtin_bit_cast(bf16x8, g_Ag2[(((w*4 + mh)*4 + kh) << 6) + l]);
#pragma unroll
            for (int mh = 0; mh < 4; ++mh)
#pragma unroll
                for (int nh = 0; nh < 4; ++nh)
                    acc[mh][nh] = __builtin_amdgcn_mfma_f32_16x16x32_bf16(Af[mh], Bf[nh], acc[mh][nh], 0, 0, 0);
        }

        // ---- LSTM elementwise (base-2, raw rcp) + score partials ----
        float Eev[4][4];
        float sp[4] = {0.f, 0.f, 0.f, 0.f};
        const int pdiag = b - jbase - r;   // diag when 16*nh == pdiag
#pragma unroll
        for (int nh = 0; nh < 4; ++nh) {
#pragma unroll
            for (int mh = 0; mh < 4; ++mh) {
                f32x4 g4 = acc[mh][nh];    // y_i, y_f, y_g, y_o (pre-scaled)
                float si = rcp_(1.f + ex2(g4[0]));
                float sf = rcp_(1.f + ex2(g4[1]));
                float so = rcp_(1.f + ex2(g4[3]));
                float tt = ex2(-__builtin_fabsf(g4[2]));
                float tg = __builtin_copysignf((1.f - tt) * rcp_(1.f + tt), -g4[2]);
                float cn = sf * cpre[nh][mh] + si * tg;
                float t2 = ex2(-__builtin_fabsf(cn) * (2.f * L2E));
                float tc = __builtin_copysignf((1.f - t2) * rcp_(1.f + t2), cn);
                float h = so * tc;
                h = (16*nh == pdiag) ? hsd[mh] : h;
                Eev[mh][nh] = h;
                sp[nh] = fmaf(qkr[mh], h, sp[nh]);
            }
        }
#pragma unroll
        for (int nh = 0; nh < 4; ++nh) {
            float v = sp[nh];
            v += __shfl_xor(v, 16, 64);
            v += __shfl_xor(v, 32, 64);
            if (q == 0) spart[w][16*nh + r] = v;
        }
        __syncthreads();

        // ---- online softmax (base-2) + ctx accumulation ----
        {
            float s_p = spart[0][l] + spart[1][l] + spart[2][l] + spart[3][l];
            float tm = s_p;
#pragma unroll
            for (int off = 1; off < 64; off <<= 1) tm = fmaxf(tm, __shfl_xor(tm, off, 64));
            float m_new = fmaxf(m_run, tm);
            float corr = ex2(m_run - m_new);
            float wp = ex2(s_p - m_new);
            l_run = fmaf(l_run, corr, wp);
            m_run = m_new;
            float wn[4];
#pragma unroll
            for (int nh = 0; nh < 4; ++nh) wn[nh] = __shfl(wp, 16*nh + r, 64);
#pragma unroll
            for (int mh = 0; mh < 4; ++mh) {
                float a = ctxa[mh] * corr;
#pragma unroll
                for (int nh = 0; nh < 4; ++nh) a = fmaf(wn[nh], Eev[mh][nh], a);
                ctxa[mh] = a;
            }
        }
    }

    // ---- epilogue: write partial (unnormalized ctx, m, l) ----
    float l_tot = l_run;
#pragma unroll
    for (int off = 1; off < 64; off <<= 1) l_tot += __shfl_xor(l_tot, off, 64);
    float* pp = g_part[bh];
#pragma unroll
    for (int mh = 0; mh < 4; ++mh) {
        float v = ctxa[mh];
        v += __shfl_xor(v, 1, 64);
        v += __shfl_xor(v, 2, 64);
        v += __shfl_xor(v, 4, 64);
        v += __shfl_xor(v, 8, 64);
        if (r == 0) pp[ebase + mh] = v;
    }
    if (tid == 0) { pp[64] = m_run; pp[65] = l_tot; }
}

// ---------------- merge: combine halves + fused output projection -----------
__global__ __launch_bounds__(64) void merge_kernel(float* __restrict__ out)
{
    __shared__ float ctxL[64];
    const int b = blockIdx.x, tid = threadIdx.x;
    const float* p0 = g_part[2*b];
    const float* p1 = g_part[2*b + 1];
    float m0 = p0[64], l0 = p0[65];
    float m1 = p1[64], l1 = p1[65];
    float M  = fmaxf(m0, m1);
    float f0 = ex2(m0 - M), f1 = ex2(m1 - M);
    float inv = rcp_(fmaf(l0, f0, l1 * f1));
    ctxL[tid] = (p0[tid]*f0 + p1[tid]*f1) * inv;
    __syncthreads();
    if (tid < OUTD) {
        float s = g_btot[tid];
        const float* wr2 = g_Wtot + tid*64;
        for (int k = 0; k < 64; ++k) s = fmaf(wr2[k], ctxL[k], s);
        out[b*OUTD + tid] = s;
    }
}

extern "C" void kernel_launch(void* const* d_in, const int* in_sizes, int n_in,
                              void* d_out, int out_size, void* d_ws, size_t ws_size,
                              hipStream_t stream) {
    const float* hidden = (const float*)d_in[0];
    const float* obs1   = (const float*)d_in[1];
    const float* obs2   = (const float*)d_in[2];
    const float* h0     = (const float*)d_in[3];
    const float* c0     = (const float*)d_in[4];
    const float* W_s    = (const float*)d_in[5];
    const float* b_s    = (const float*)d_in[6];
    const float* W_v    = (const float*)d_in[7];
    const float* b_v    = (const float*)d_in[8];
    const float* W_hs   = (const float*)d_in[9];
    const float* b_hs   = (const float*)d_in[10];
    const float* W_ih   = (const float*)d_in[11];
    const float* b_ih   = (const float*)d_in[12];
    const float* W_hh   = (const float*)d_in[13];
    const float* b_hh   = (const float*)d_in[14];
    const float* Wq     = (const float*)d_in[15];
    const float* Wk     = (const float*)d_in[16];
    const float* Wv     = (const float*)d_in[17];
    const float* W_in   = (const float*)d_in[18];
    const float* b_in   = (const float*)d_in[19];
    const float* W_out  = (const float*)d_in[20];
    const float* b_out  = (const float*)d_in[21];
    const float* W_o    = (const float*)d_in[22];
    const float* b_o    = (const float*)d_in[23];

    prepW<<<dim3(8), dim3(256), 0, stream>>>(
        W_ih, b_ih, W_hh, b_hh, Wq, Wk, Wv, W_in, W_hs, W_s, b_s, W_v, b_v);
    prepW2<<<dim3(2), dim3(256), 0, stream>>>(b_in, W_out, b_out, W_o, b_o);
    prepH<<<dim3(NN), dim3(256), 0, stream>>>(hidden, b_hs);
    row_kernel<<<dim3(2*NN), dim3(256), 0, stream>>>(obs1, obs2, h0, c0);
    merge_kernel<<<dim3(NN), dim3(64), 0, stream>>>((float*)d_out);
}

// Round 4
// 118.879 us; speedup vs baseline: 3.7573x; 1.5040x over previous
//
#include <hip/hip_runtime.h>
#include <cstdint>

#define NN 512
#define EE 64
#define HIDD 256
#define OUTD 32
#define L2E 1.4426950408889634f

typedef __bf16 bf16x8 __attribute__((ext_vector_type(8)));
typedef float f32x4 __attribute__((ext_vector_type(4)));

// -------- device-global scratch (fully rewritten every call; deterministic) --------
__device__ float g_hs[NN*EE];
__device__ float g_qk[NN*EE];          // log2e-scaled (Wk_comb^T @ q2) per row
__device__ float g_Wcomb[3*EE*EE];
__device__ float g_WhsT[HIDD*EE];
__device__ float g_M2T[EE*EE];
__device__ float g_cvec[EE];
__device__ uint4 g_Ag2[4096];          // bf16 A-fragments, gate-scaled
__device__ float g_biasI[256];
__device__ float g_embW[EE*4];
__device__ float g_Wtot[OUTD*EE];
__device__ float g_btot[OUTD];

__device__ __forceinline__ float ex2(float x){ return __builtin_amdgcn_exp2f(x); }
__device__ __forceinline__ float rcp_(float x){ return __builtin_amdgcn_rcpf(x); }

// ---------------- prepW: weight packing ----------------
__global__ __launch_bounds__(256) void prepW(
    const float* __restrict__ W_ih, const float* __restrict__ b_ih,
    const float* __restrict__ W_hh, const float* __restrict__ b_hh,
    const float* __restrict__ Wq, const float* __restrict__ Wk, const float* __restrict__ Wv,
    const float* __restrict__ W_in, const float* __restrict__ W_hs,
    const float* __restrict__ W_s, const float* __restrict__ b_s,
    const float* __restrict__ W_v, const float* __restrict__ b_v)
{
    const int blk = blockIdx.x, tid = threadIdx.x;
    if (blk < 4) {
        const int w = blk;
#pragma unroll
        for (int ii = 0; ii < 4; ++ii) {
            int idx = ii*256 + tid;            // (mh*4+kh)*64 + lane
            int lane = idx & 63;
            int kh = (idx >> 6) & 3;
            int mh = idx >> 8;
            int m = lane & 15;
            int qq = m >> 2, gate = m & 3;
            int e = 16*w + 4*qq + mh;
            int o = gate*64 + e;
            int kb = kh*32 + (lane >> 4)*8;
            float sc = (gate == 2) ? (-2.f*L2E) : (-L2E);
            bf16x8 vv;
#pragma unroll
            for (int j = 0; j < 8; ++j) {
                int k = kb + j;
                float raw = (k < 64) ? W_ih[o*64 + k] : W_hh[o*64 + (k - 64)];
                vv[j] = (__bf16)(sc * raw);
            }
            g_Ag2[(((w*4 + mh)*4 + kh) << 6) + lane] = __builtin_bit_cast(uint4, vv);
        }
    } else if (blk == 4) {
        {
            int e = tid >> 2, gate = tid & 3, o = gate*64 + e;
            float sc = (gate == 2) ? (-2.f*L2E) : (-L2E);
            g_biasI[tid] = sc * (b_ih[o] + b_hh[o]);
        }
        if (tid < 64) {
            int e = tid;
            if (e < 32) {
                g_embW[e*4+0] = W_s[e*2]; g_embW[e*4+1] = W_s[e*2+1]; g_embW[e*4+2] = b_s[e];
            } else {
                g_embW[e*4+0] = 4.f*W_v[(e-32)*2]; g_embW[e*4+1] = 4.f*W_v[(e-32)*2+1]; g_embW[e*4+2] = b_v[e-32];
            }
            g_embW[e*4+3] = 0.f;
        }
        for (int idx = tid; idx < HIDD*EE; idx += 256) {
            int k = idx >> 6, e = idx & 63;
            g_WhsT[idx] = W_hs[e*HIDD + k];
        }
    } else {
        int t = blk - 5;
        const float* W2 = W_in + t*4096;
        const float* W1 = (t == 0) ? Wq : ((t == 1) ? Wk : Wv);
        for (int idx = tid; idx < 4096; idx += 256) {
            int a = idx >> 6, c = idx & 63;
            float s = 0.f;
            for (int m = 0; m < 64; ++m) s = fmaf(W2[a*64 + m], W1[m*64 + c], s);
            g_Wcomb[t*4096 + idx] = s;
        }
    }
}

// ---------------- prepW2: M2T/cvec (blk0) + fused output proj (blk1) --------
__global__ __launch_bounds__(256) void prepW2(
    const float* __restrict__ b_in, const float* __restrict__ W_out,
    const float* __restrict__ b_out, const float* __restrict__ W_o,
    const float* __restrict__ b_o)
{
    const int tid = threadIdx.x;
    if (blockIdx.x == 0) {
        const float* Wqc = g_Wcomb;
        const float* Wkc = g_Wcomb + 4096;
        for (int idx = tid; idx < 4096; idx += 256) {
            int c = idx >> 6, e = idx & 63;
            float s = 0.f;
            for (int a = 0; a < 64; ++a) s = fmaf(Wkc[a*64 + e], Wqc[a*64 + c], s);
            g_M2T[idx] = s * (L2E * 0.125f);
        }
        if (tid < 64) {
            float s = 0.f;
            for (int a = 0; a < 64; ++a) s = fmaf(g_Wcomb[4096 + a*64 + tid], b_in[a], s);
            g_cvec[tid] = s * (L2E * 0.125f);
        }
    } else {
        __shared__ float Wtmp[4096];
        __shared__ float bb[64];
        for (int idx = tid; idx < 4096; idx += 256) {
            int i = idx >> 6, jj = idx & 63;
            float s = 0.f;
            for (int k = 0; k < 64; ++k) s = fmaf(W_out[i*64 + k], g_Wcomb[2*4096 + k*64 + jj], s);
            Wtmp[idx] = s;
        }
        if (tid < 64) {
            float s = 0.f;
            for (int k = 0; k < 64; ++k) s = fmaf(W_out[tid*64 + k], b_in[128 + k], s);
            bb[tid] = s + b_out[tid];
        }
        __syncthreads();
        for (int idx = tid; idx < OUTD*64; idx += 256) {
            int o = idx >> 6, jj = idx & 63;
            float s = 0.f;
            for (int i = 0; i < 64; ++i) s = fmaf(W_o[o*64 + i], Wtmp[i*64 + jj], s);
            g_Wtot[idx] = s;
        }
        if (tid < OUTD) {
            float s = 0.f;
            for (int i = 0; i < 64; ++i) s = fmaf(W_o[tid*64 + i], bb[i], s);
            g_btot[tid] = s + b_o[tid];
        }
    }
}

// ---------------- prepH: per-row hs and qk (coalesced) ----------------------
__global__ __launch_bounds__(256) void prepH(
    const float* __restrict__ hidden, const float* __restrict__ b_hs)
{
    __shared__ float hid[HIDD];
    __shared__ float part[4][64];
    __shared__ float hsL[64];
    const int b = blockIdx.x, tid = threadIdx.x;
    hid[tid] = hidden[b*HIDD + tid];
    __syncthreads();
    const int e = tid & 63, kq = tid >> 6;
    float s = 0.f;
    for (int k = 0; k < 64; ++k) {
        int kk = kq*64 + k;
        s = fmaf(g_WhsT[kk*64 + e], hid[kk], s);
    }
    part[kq][e] = s;
    __syncthreads();
    if (tid < 64) {
        float v = part[0][tid] + part[1][tid] + part[2][tid] + part[3][tid] + b_hs[tid];
        g_hs[b*EE + tid] = v;
        hsL[tid] = v;
    }
    __syncthreads();
    float s2 = 0.f;
    for (int k = 0; k < 16; ++k) {
        int kk = kq*16 + k;
        s2 = fmaf(g_M2T[kk*64 + e], hsL[kk], s2);
    }
    part[kq][e] = s2;
    __syncthreads();
    if (tid < 64)
        g_qk[b*EE + tid] = part[0][tid] + part[1][tid] + part[2][tid] + part[3][tid] + g_cvec[tid];
}

// ---------------- row kernel: one block per row b, 8 tiles ------------------
__global__ __launch_bounds__(256) void row_kernel(
    const float* __restrict__ obs1, const float* __restrict__ obs2,
    const float* __restrict__ h0, const float* __restrict__ c0,
    float* __restrict__ out)
{
    // swizzled tiles: byte-in-row XOR ((row&7)<<4); staged linear via pre-swizzled source
    __shared__ __align__(16) float Hs[64*64];            // h tile f32, 256B rows
    __shared__ __align__(16) float Cs[64*64];            // c tile f32, 256B rows
    __shared__ __align__(16) unsigned short Xe[64*64];   // embed bf16, 128B rows
    __shared__ float spart[4][64];
    __shared__ float embw[64][4];
    __shared__ float ctxE[64];

    const int b = blockIdx.x, tid = threadIdx.x;
    const int w = tid >> 6, l = tid & 63;
    const int r = l & 15, q = l >> 4;
    const int p4 = tid >> 2, a4 = tid & 3;
    const int ebase = 16*w + 4*q;

    const size_t rowbase = (size_t)b * NN * EE;
    const float* h0r = h0 + rowbase;
    const float* c0r = c0 + rowbase;

    // --- per-thread persistent state ---
    const float4 qk4 = *(const float4*)(g_qk + b*64 + ebase);
    const float4 hs4 = *(const float4*)(g_hs + b*64 + ebase);
    f32x4 biasv[4];
#pragma unroll
    for (int mh = 0; mh < 4; ++mh) {
        float4 t4 = *(const float4*)(g_biasI + (ebase + mh)*4);
        biasv[mh][0]=t4.x; biasv[mh][1]=t4.y; biasv[mh][2]=t4.z; biasv[mh][3]=t4.w;
    }
    const float ob1x = obs1[b*2], ob1y = obs1[b*2+1];
    const float ob2x = obs2[b*2], ob2y = obs2[b*2+1];
    const float velbx = ob2x - ob1x, velby = ob2y - ob1y;

    if (tid < 64) *(float4*)&embw[tid][0] = *(const float4*)(g_embW + tid*4);

    // --- staging helper: 4 chunks of 1KB per wave per tile, pre-swizzled src ---
    auto stage = [&](const float* gsrc, void* ldsbase) {
#pragma unroll
        for (int j = 0; j < 4; ++j) {
            const int row = w*16 + j*4 + (l >> 4);
            const int cb  = (l & 15) * 16;
            const char* g = (const char*)gsrc + row*256 + (cb ^ ((row & 7) << 4));
            char* lp = (char*)ldsbase + (w*16 + j*4)*256;
            __builtin_amdgcn_global_load_lds(
                (const __attribute__((address_space(1))) void*)g,
                (__attribute__((address_space(3))) void*)lp, 16, 0, 0);
        }
    };
    // --- embed compute for tile starting at jb, thread covers (row p4, e-quarter a4) ---
    auto embed = [&](int jb) {
        const int jn = jb + p4;
        const float2 o2 = *(const float2*)(obs2 + jn*2);
        const float2 o1 = *(const float2*)(obs1 + jn*2);
        const float fx = o2.x - ob2x, fy = o2.y - ob2y;
        const float gx = (o2.x - o1.x) - velbx, gy = (o2.y - o1.y) - velby;
        const bool sph = (a4 < 2);
        const float u0 = sph ? fx : gx, u1 = sph ? fy : gy;
        bf16x8 pa, pb;
#pragma unroll
        for (int i = 0; i < 8; ++i) {
            float4 wv = *(const float4*)&embw[16*a4 + i][0];
            pa[i] = (__bf16)fmaxf(fmaf(wv.x, u0, fmaf(wv.y, u1, wv.z)), 0.f);
        }
#pragma unroll
        for (int i = 0; i < 8; ++i) {
            float4 wv = *(const float4*)&embw[16*a4 + 8 + i][0];
            pb[i] = (__bf16)fmaxf(fmaf(wv.x, u0, fmaf(wv.y, u1, wv.z)), 0.f);
        }
        const int swz = (p4 & 7) << 4;
        *(bf16x8*)((char*)Xe + p4*128 + ((a4*32)      ^ swz)) = pa;
        *(bf16x8*)((char*)Xe + p4*128 + ((a4*32 + 16) ^ swz)) = pb;
    };

    // --- prologue: stage tile 0 ---
    stage(h0r, Hs);
    stage(c0r, Cs);
    __syncthreads();                 // embw visible
    embed(0);
    asm volatile("s_waitcnt vmcnt(0)" ::: "memory");
    __syncthreads();                 // tile 0 fully staged

    float m_run = -__builtin_inff(), l_run = 0.f;
    float ctxa[4] = {0.f, 0.f, 0.f, 0.f};

    for (int t = 0; t < 8; ++t) {
        const int jbase = t*64;

        // ---- phase A: gates MFMA (B from swizzled LDS; A streamed from L2) ----
        f32x4 acc[4][4];
#pragma unroll
        for (int mh = 0; mh < 4; ++mh)
#pragma unroll
            for (int nh = 0; nh < 4; ++nh) acc[mh][nh] = biasv[mh];
#pragma unroll
        for (int kh = 0; kh < 4; ++kh) {
            bf16x8 Bf[4];
            if (kh < 2) {
#pragma unroll
                for (int nh = 0; nh < 4; ++nh) {
                    const int p = 16*nh + r;
                    Bf[nh] = *(const bf16x8*)((const char*)Xe + p*128 +
                              ((kh*64 + q*16) ^ ((p & 7) << 4)));
                }
            } else {
#pragma unroll
                for (int nh = 0; nh < 4; ++nh) {
                    const int p = 16*nh + r;
                    const int sw = (p & 7) << 4;
                    const char* hb = (const char*)Hs + p*256;
                    f32x4 f0 = *(const f32x4*)(hb + (((kh-2)*128 + q*32)      ^ sw));
                    f32x4 f1 = *(const f32x4*)(hb + (((kh-2)*128 + q*32 + 16) ^ sw));
                    bf16x8 o;
                    o[0]=(__bf16)f0[0]; o[1]=(__bf16)f0[1]; o[2]=(__bf16)f0[2]; o[3]=(__bf16)f0[3];
                    o[4]=(__bf16)f1[0]; o[5]=(__bf16)f1[1]; o[6]=(__bf16)f1[2]; o[7]=(__bf16)f1[3];
                    Bf[nh] = o;
                }
            }
            bf16x8 Af[4];
#pragma unroll
            for (int mh = 0; mh < 4; ++mh)
                Af[mh] = __builtin_bit_cast(bf16x8, g_Ag2[(((w*4 + mh)*4 + kh) << 6) + l]);
#pragma unroll
            for (int mh = 0; mh < 4; ++mh)
#pragma unroll
                for (int nh = 0; nh < 4; ++nh)
                    acc[mh][nh] = __builtin_amdgcn_mfma_f32_16x16x32_bf16(Af[mh], Bf[nh], acc[mh][nh], 0, 0, 0);
        }
        // ---- c fragment from swizzled LDS ----
        f32x4 cpre[4];
#pragma unroll
        for (int nh = 0; nh < 4; ++nh) {
            const int p = 16*nh + r;
            cpre[nh] = *(const f32x4*)((const char*)Cs + p*256 +
                        ((64*w + 16*q) ^ ((p & 7) << 4)));
        }
        __syncthreads();   // all LDS reads of tile t complete

        // ---- phase C: prefetch tile t+1 (direct-to-LDS) + next embed ----
        if (t < 7) {
            stage(h0r + (jbase + 64)*EE, Hs);
            stage(c0r + (jbase + 64)*EE, Cs);
            embed(jbase + 64);
        }

        // ---- phase D: LSTM elementwise (base-2) + score partials ----
        float Eev[4][4];
        float sp[4] = {0.f, 0.f, 0.f, 0.f};
        const int pdiag = b - jbase - r;
#pragma unroll
        for (int nh = 0; nh < 4; ++nh) {
#pragma unroll
            for (int mh = 0; mh < 4; ++mh) {
                f32x4 g4 = acc[mh][nh];
                float si = rcp_(1.f + ex2(g4[0]));
                float sf = rcp_(1.f + ex2(g4[1]));
                float so = rcp_(1.f + ex2(g4[3]));
                float tt = ex2(-__builtin_fabsf(g4[2]));
                float tg = __builtin_copysignf((1.f - tt) * rcp_(1.f + tt), -g4[2]);
                float cn = sf * cpre[nh][mh] + si * tg;
                float t2 = ex2(-__builtin_fabsf(cn) * (2.f * L2E));
                float tc = __builtin_copysignf((1.f - t2) * rcp_(1.f + t2), cn);
                float h = so * tc;
                h = (16*nh == pdiag) ? ((const float*)&hs4)[mh] : h;
                Eev[mh][nh] = h;
                sp[nh] = fmaf(((const float*)&qk4)[mh], h, sp[nh]);
            }
        }
#pragma unroll
        for (int nh = 0; nh < 4; ++nh) {
            float v = sp[nh];
            v += __shfl_xor(v, 16, 64);
            v += __shfl_xor(v, 32, 64);
            if (q == 0) spart[w][16*nh + r] = v;
        }
        __syncthreads();

        // ---- phase E: online softmax (base-2) + ctx accumulation ----
        {
            float s_p = spart[0][l] + spart[1][l] + spart[2][l] + spart[3][l];
            float tm = s_p;
#pragma unroll
            for (int off = 1; off < 64; off <<= 1) tm = fmaxf(tm, __shfl_xor(tm, off, 64));
            float m_new = fmaxf(m_run, tm);
            float corr = ex2(m_run - m_new);
            float wp = ex2(s_p - m_new);
            l_run = fmaf(l_run, corr, wp);
            m_run = m_new;
            float wn[4];
#pragma unroll
            for (int nh = 0; nh < 4; ++nh) wn[nh] = __shfl(wp, 16*nh + r, 64);
#pragma unroll
            for (int mh = 0; mh < 4; ++mh) {
                float a = ctxa[mh] * corr;
#pragma unroll
                for (int nh = 0; nh < 4; ++nh) a = fmaf(wn[nh], Eev[mh][nh], a);
                ctxa[mh] = a;
            }
        }
        // ---- end of tile: make next tile's staging visible ----
        if (t < 7) {
            asm volatile("s_waitcnt vmcnt(0)" ::: "memory");
        }
        __syncthreads();
    }

    // ---- epilogue: normalize, reduce, fused output projection ----
    float l_tot = l_run;
#pragma unroll
    for (int off = 1; off < 64; off <<= 1) l_tot += __shfl_xor(l_tot, off, 64);
    const float inv = rcp_(l_tot);
#pragma unroll
    for (int mh = 0; mh < 4; ++mh) {
        float v = ctxa[mh];
        v += __shfl_xor(v, 1, 64);
        v += __shfl_xor(v, 2, 64);
        v += __shfl_xor(v, 4, 64);
        v += __shfl_xor(v, 8, 64);
        if (r == 0) ctxE[ebase + mh] = v * inv;
    }
    __syncthreads();
    if (tid < OUTD) {
        float s = g_btot[tid];
        const float* wr2 = g_Wtot + tid*64;
        for (int k = 0; k < 64; ++k) s = fmaf(wr2[k], ctxE[k], s);
        out[b*OUTD + tid] = s;
    }
}

extern "C" void kernel_launch(void* const* d_in, const int* in_sizes, int n_in,
                              void* d_out, int out_size, void* d_ws, size_t ws_size,
                              hipStream_t stream) {
    const float* hidden = (const float*)d_in[0];
    const float* obs1   = (const float*)d_in[1];
    const float* obs2   = (const float*)d_in[2];
    const float* h0     = (const float*)d_in[3];
    const float* c0     = (const float*)d_in[4];
    const float* W_s    = (const float*)d_in[5];
    const float* b_s    = (const float*)d_in[6];
    const float* W_v    = (const float*)d_in[7];
    const float* b_v    = (const float*)d_in[8];
    const float* W_hs   = (const float*)d_in[9];
    const float* b_hs   = (const float*)d_in[10];
    const float* W_ih   = (const float*)d_in[11];
    const float* b_ih   = (const float*)d_in[12];
    const float* W_hh   = (const float*)d_in[13];
    const float* b_hh   = (const float*)d_in[14];
    const float* Wq     = (const float*)d_in[15];
    const float* Wk     = (const float*)d_in[16];
    const float* Wv     = (const float*)d_in[17];
    const float* W_in   = (const float*)d_in[18];
    const float* b_in   = (const float*)d_in[19];
    const float* W_out  = (const float*)d_in[20];
    const float* b_out  = (const float*)d_in[21];
    const float* W_o    = (const float*)d_in[22];
    const float* b_o    = (const float*)d_in[23];

    prepW<<<dim3(8), dim3(256), 0, stream>>>(
        W_ih, b_ih, W_hh, b_hh, Wq, Wk, Wv, W_in, W_hs, W_s, b_s, W_v, b_v);
    prepW2<<<dim3(2), dim3(256), 0, stream>>>(b_in, W_out, b_out, W_o, b_o);
    prepH<<<dim3(NN), dim3(256), 0, stream>>>(hidden, b_hs);
    row_kernel<<<dim3(NN), dim3(256), 0, stream>>>(obs1, obs2, h0, c0, (float*)d_out);
}